// Round 1
// baseline (214.455 us; speedup 1.0000x reference)
//
#include <hip/hip_runtime.h>
#include <hip/hip_bf16.h>
#include <stdint.h>

#define HID 1024
#define BLKDIM 128
#define BK 32
#define NK (HID / BK)   // 32 K-steps

using short8 = __attribute__((ext_vector_type(8))) short;
using f32x4  = __attribute__((ext_vector_type(4))) float;

__device__ __forceinline__ uint32_t bfround(float f) {
    uint32_t u = __builtin_bit_cast(uint32_t, f);
    return (u + 0x7FFFu + ((u >> 16) & 1u)) >> 16;   // RNE to bf16, as uint16 in low bits
}

__device__ __forceinline__ void store16(ushort* dst, float4 v0, float4 v1, float4 v2, float4 v3) {
    // pack 16 fp32 -> 16 bf16 -> two 16B LDS writes
    uint4 w0, w1;
    w0.x = bfround(v0.x) | (bfround(v0.y) << 16);
    w0.y = bfround(v0.z) | (bfround(v0.w) << 16);
    w0.z = bfround(v1.x) | (bfround(v1.y) << 16);
    w0.w = bfround(v1.z) | (bfround(v1.w) << 16);
    w1.x = bfround(v2.x) | (bfround(v2.y) << 16);
    w1.y = bfround(v2.z) | (bfround(v2.w) << 16);
    w1.z = bfround(v3.x) | (bfround(v3.y) << 16);
    w1.w = bfround(v3.z) | (bfround(v3.w) << 16);
    uint4* d = reinterpret_cast<uint4*>(dst);
    d[0] = w0;
    d[1] = w1;
}

__global__ __launch_bounds__(256, 2)
void sdd_bf16_kernel(const float* __restrict__ x, const float* __restrict__ w1,
                     const int* __restrict__ rind, const int* __restrict__ cind,
                     float* __restrict__ out) {
    __shared__ ushort sA[2][BLKDIM * BK];
    __shared__ ushort sB[2][BLKDIM * BK];

    const int k = blockIdx.x;
    const int t = threadIdx.x;
    const int r = rind[k];
    const int c = cind[k];
    const float* Abase = x  + (size_t)r * BLKDIM * HID;
    const float* Bbase = w1 + (size_t)c * BLKDIM * HID;

    // staging role: each thread owns 16 contiguous k-elements of one row
    const int srow  = t >> 1;        // 0..127
    const int shalf = t & 1;         // k-offset 16*shalf within the 32-wide K-step
    const float* aptr = Abase + (size_t)srow * HID + shalf * 16;
    const float* bptr = Bbase + (size_t)srow * HID + shalf * 16;
    const int soff = srow * BK + shalf * 16;

    // compute role: 4 waves, each owns a 64x64 quadrant
    const int wv   = t >> 6;
    const int lane = t & 63;
    const int wr = (wv >> 1) * 64;
    const int wc = (wv & 1) * 64;
    const int lr = lane & 15;
    const int lk = (lane >> 4) * 8;

    f32x4 acc[4][4];
#pragma unroll
    for (int m = 0; m < 4; ++m)
#pragma unroll
        for (int n = 0; n < 4; ++n)
            acc[m][n] = (f32x4){0.f, 0.f, 0.f, 0.f};

    float4 ra[4], rb[4];
#pragma unroll
    for (int i = 0; i < 4; ++i) {
        ra[i] = *reinterpret_cast<const float4*>(aptr + i * 4);
        rb[i] = *reinterpret_cast<const float4*>(bptr + i * 4);
    }
    store16(&sA[0][soff], ra[0], ra[1], ra[2], ra[3]);
    store16(&sB[0][soff], rb[0], rb[1], rb[2], rb[3]);
    __syncthreads();

    for (int kt = 0; kt < NK; ++kt) {
        const int cur = kt & 1;
        if (kt + 1 < NK) {
            const float* ap = aptr + (kt + 1) * BK;
            const float* bp = bptr + (kt + 1) * BK;
#pragma unroll
            for (int i = 0; i < 4; ++i) {
                ra[i] = *reinterpret_cast<const float4*>(ap + i * 4);
                rb[i] = *reinterpret_cast<const float4*>(bp + i * 4);
            }
        }
        const ushort* sa = sA[cur];
        const ushort* sb = sB[cur];
        short8 aF[4], bF[4];
#pragma unroll
        for (int m = 0; m < 4; ++m)
            aF[m] = *reinterpret_cast<const short8*>(&sa[(wr + m * 16 + lr) * BK + lk]);
#pragma unroll
        for (int n = 0; n < 4; ++n)
            bF[n] = *reinterpret_cast<const short8*>(&sb[(wc + n * 16 + lr) * BK + lk]);
#pragma unroll
        for (int m = 0; m < 4; ++m)
#pragma unroll
            for (int n = 0; n < 4; ++n)
                acc[m][n] = __builtin_amdgcn_mfma_f32_16x16x32_bf16(aF[m], bF[n], acc[m][n], 0, 0, 0);
        if (kt + 1 < NK) {
            store16(&sA[cur ^ 1][soff], ra[0], ra[1], ra[2], ra[3]);
            store16(&sB[cur ^ 1][soff], rb[0], rb[1], rb[2], rb[3]);
        }
        __syncthreads();
    }

    // epilogue: C/D mapping (16x16x32): col = lane&15, row = (lane>>4)*4 + j
    float* op = out + (size_t)k * (BLKDIM * BLKDIM);
    const int rbase = wr + (lane >> 4) * 4;
#pragma unroll
    for (int m = 0; m < 4; ++m)
#pragma unroll
        for (int n = 0; n < 4; ++n) {
            const int col = wc + n * 16 + lr;
#pragma unroll
            for (int j = 0; j < 4; ++j)
                op[(size_t)(rbase + m * 16 + j) * BLKDIM + col] = acc[m][n][j];
        }
}

extern "C" void kernel_launch(void* const* d_in, const int* in_sizes, int n_in,
                              void* d_out, int out_size, void* d_ws, size_t ws_size,
                              hipStream_t stream) {
    const float* x  = (const float*)d_in[0];
    const float* w1 = (const float*)d_in[1];
    const int* ri   = (const int*)d_in[2];
    const int* ci   = (const int*)d_in[3];
    float* out      = (float*)d_out;
    const int nnz   = in_sizes[2];

    hipLaunchKernelGGL(sdd_bf16_kernel, dim3(nnz), dim3(256), 0, stream,
                       x, w1, ri, ci, out);
}

// Round 3
// 143.121 us; speedup vs baseline: 1.4984x; 1.4984x over previous
//
#include <hip/hip_runtime.h>
#include <hip/hip_bf16.h>
#include <stdint.h>

#define HID 1024
#define BLKDIM 128
#define BK 32
#define NK (HID / BK)   // 32 K-steps

using short8 = __attribute__((ext_vector_type(8))) short;
using f32x4  = __attribute__((ext_vector_type(4))) float;

__device__ __forceinline__ uint32_t bfround(float f) {
    uint32_t u = __builtin_bit_cast(uint32_t, f);
    return (u + 0x7FFFu + ((u >> 16) & 1u)) >> 16;   // RNE to bf16
}

__device__ __forceinline__ void gld16(const ushort* g, const ushort* lds_base) {
    // async global->LDS, 16B per lane; LDS dest = wave-uniform base + lane*16
    __builtin_amdgcn_global_load_lds(
        (const __attribute__((address_space(1))) void*)g,
        (__attribute__((address_space(3))) void*)lds_base, 16, 0, 0);
}

// ---------------- pre-pass: fp32 -> bf16, 8 elems/thread ----------------
__global__ __launch_bounds__(256)
void cvt_bf16_kernel(const float* __restrict__ src, uint4* __restrict__ dst, int n8) {
    int i = blockIdx.x * blockDim.x + threadIdx.x;
    if (i >= n8) return;
    const float4* s = reinterpret_cast<const float4*>(src) + (size_t)i * 2;
    float4 v0 = s[0], v1 = s[1];
    uint4 w;
    w.x = bfround(v0.x) | (bfround(v0.y) << 16);
    w.y = bfround(v0.z) | (bfround(v0.w) << 16);
    w.z = bfround(v1.x) | (bfround(v1.y) << 16);
    w.w = bfround(v1.z) | (bfround(v1.w) << 16);
    dst[i] = w;
}

// ---------------- main GEMM: 128x256 tile (2 output blocks), bf16 MFMA ----------------
__global__ __launch_bounds__(512, 2)
void sdd_pair_kernel(const ushort* __restrict__ xb, const ushort* __restrict__ wb,
                     const int* __restrict__ rind, const int* __restrict__ cind,
                     float* __restrict__ out) {
    __shared__ ushort sA[2][BLKDIM * BK];      // 8 KB per buf
    __shared__ ushort sB[2][2 * BLKDIM * BK];  // 16 KB per buf

    int g = blockIdx.x;
    const int nwg = gridDim.x;
    if ((nwg & 7) == 0) {                      // bijective XCD swizzle
        const int cpx = nwg >> 3;
        g = (g & 7) * cpx + (g >> 3);
    }
    const int k0 = g * 2;
    const int r  = rind[k0];

    const int t = threadIdx.x;
    const int w = t >> 6;          // wave 0..7
    const int lane = t & 63;

    // ---- staging addresses (per-lane global, wave-uniform LDS base) ----
    // A: wave w covers rows w*16 .. w*16+15 of the 128-row x block
    const int arow = w * 16 + (lane >> 2);
    const ushort* ag = xb + (size_t)(r * BLKDIM + arow) * HID + (lane & 3) * 8;
    // B: wave w covers rows w*32 .. w*32+31 of the 256-row (2-block) w1 panel
    const int brow0 = w * 32 + (lane >> 2);
    const int brow1 = brow0 + 16;
    const int cA = cind[k0 + (brow0 >> 7)];
    const int cB = cind[k0 + (brow1 >> 7)];
    const ushort* bg0 = wb + (size_t)(cA * BLKDIM + (brow0 & 127)) * HID + (lane & 3) * 8;
    const ushort* bg1 = wb + (size_t)(cB * BLKDIM + (brow1 & 127)) * HID + (lane & 3) * 8;

    // ---- compute role: 8 waves as 2 (rows) x 4 (cols), each 64x64 ----
    const int wr = (w >> 2) * 64;
    const int wc = (w & 3) * 64;
    const int lr = lane & 15;
    const int lk = (lane >> 4) * 8;

    f32x4 acc[4][4];
#pragma unroll
    for (int m = 0; m < 4; ++m)
#pragma unroll
        for (int n = 0; n < 4; ++n)
            acc[m][n] = (f32x4){0.f, 0.f, 0.f, 0.f};

    auto stage = [&](int buf, int kt) {
        gld16(ag  + kt * BK, &sA[buf][w * 512]);
        gld16(bg0 + kt * BK, &sB[buf][w * 1024]);
        gld16(bg1 + kt * BK, &sB[buf][w * 1024 + 512]);
    };

    stage(0, 0);
    int cur = 0;
    for (int kt = 0; kt < NK; ++kt) {
        __syncthreads();               // drains vmcnt -> buf[cur] ready
        if (kt + 1 < NK) stage(cur ^ 1, kt + 1);   // async loads overlap compute
        const ushort* sa = sA[cur];
        const ushort* sb = sB[cur];
        short8 aF[4], bF[4];
#pragma unroll
        for (int m = 0; m < 4; ++m)
            aF[m] = *reinterpret_cast<const short8*>(&sa[(wr + m * 16 + lr) * BK + lk]);
#pragma unroll
        for (int n = 0; n < 4; ++n)
            bF[n] = *reinterpret_cast<const short8*>(&sb[(wc + n * 16 + lr) * BK + lk]);
#pragma unroll
        for (int m = 0; m < 4; ++m)
#pragma unroll
            for (int n = 0; n < 4; ++n)
                acc[m][n] = __builtin_amdgcn_mfma_f32_16x16x32_bf16(aF[m], bF[n], acc[m][n], 0, 0, 0);
        cur ^= 1;
    }

    // ---- epilogue: C/D mapping col=lane&15, row=(lane>>4)*4+j ----
    const int blk = (w & 3) >> 1;                    // which of the 2 output blocks
    float* op = out + (size_t)(k0 + blk) * (BLKDIM * BLKDIM);
    const int colbase = (wc & 64) ? 64 : 0;          // col base within the 128-wide block
    const int rbase = wr + (lane >> 4) * 4;
#pragma unroll
    for (int m = 0; m < 4; ++m)
#pragma unroll
        for (int n = 0; n < 4; ++n) {
            const int col = colbase + n * 16 + lr;
#pragma unroll
            for (int j = 0; j < 4; ++j)
                op[(size_t)(rbase + m * 16 + j) * BLKDIM + col] = acc[m][n][j];
        }
}

// ---------------- fallback (round-1 kernel) for ws-too-small / odd nnz ----------------
__device__ __forceinline__ void store16f(ushort* dst, float4 v0, float4 v1, float4 v2, float4 v3) {
    uint4 w0, w1;
    w0.x = bfround(v0.x) | (bfround(v0.y) << 16);
    w0.y = bfround(v0.z) | (bfround(v0.w) << 16);
    w0.z = bfround(v1.x) | (bfround(v1.y) << 16);
    w0.w = bfround(v1.z) | (bfround(v1.w) << 16);
    w1.x = bfround(v2.x) | (bfround(v2.y) << 16);
    w1.y = bfround(v2.z) | (bfround(v2.w) << 16);
    w1.z = bfround(v3.x) | (bfround(v3.y) << 16);
    w1.w = bfround(v3.z) | (bfround(v3.w) << 16);
    uint4* d = reinterpret_cast<uint4*>(dst);
    d[0] = w0; d[1] = w1;
}

__global__ __launch_bounds__(256, 2)
void sdd_bf16_kernel(const float* __restrict__ x, const float* __restrict__ w1,
                     const int* __restrict__ rind, const int* __restrict__ cind,
                     float* __restrict__ out) {
    __shared__ ushort sA[2][BLKDIM * BK];
    __shared__ ushort sB[2][BLKDIM * BK];
    const int k = blockIdx.x;
    const int t = threadIdx.x;
    const int r = rind[k];
    const int c = cind[k];
    const float* Abase = x  + (size_t)r * BLKDIM * HID;
    const float* Bbase = w1 + (size_t)c * BLKDIM * HID;
    const int srow = t >> 1, shalf = t & 1;
    const float* aptr = Abase + (size_t)srow * HID + shalf * 16;
    const float* bptr = Bbase + (size_t)srow * HID + shalf * 16;
    const int soff = srow * BK + shalf * 16;
    const int wv = t >> 6, lane = t & 63;
    const int wr = (wv >> 1) * 64, wc = (wv & 1) * 64;
    const int lr = lane & 15, lk = (lane >> 4) * 8;
    f32x4 acc[4][4];
#pragma unroll
    for (int m = 0; m < 4; ++m)
#pragma unroll
        for (int n = 0; n < 4; ++n) acc[m][n] = (f32x4){0.f, 0.f, 0.f, 0.f};
    float4 ra[4], rb[4];
#pragma unroll
    for (int i = 0; i < 4; ++i) {
        ra[i] = *reinterpret_cast<const float4*>(aptr + i * 4);
        rb[i] = *reinterpret_cast<const float4*>(bptr + i * 4);
    }
    store16f(&sA[0][soff], ra[0], ra[1], ra[2], ra[3]);
    store16f(&sB[0][soff], rb[0], rb[1], rb[2], rb[3]);
    __syncthreads();
    for (int kt = 0; kt < NK; ++kt) {
        const int cur = kt & 1;
        if (kt + 1 < NK) {
            const float* ap = aptr + (kt + 1) * BK;
            const float* bp = bptr + (kt + 1) * BK;
#pragma unroll
            for (int i = 0; i < 4; ++i) {
                ra[i] = *reinterpret_cast<const float4*>(ap + i * 4);
                rb[i] = *reinterpret_cast<const float4*>(bp + i * 4);
            }
        }
        const ushort* sa = sA[cur];
        const ushort* sb = sB[cur];
        short8 aF[4], bF[4];
#pragma unroll
        for (int m = 0; m < 4; ++m) aF[m] = *reinterpret_cast<const short8*>(&sa[(wr + m * 16 + lr) * BK + lk]);
#pragma unroll
        for (int n = 0; n < 4; ++n) bF[n] = *reinterpret_cast<const short8*>(&sb[(wc + n * 16 + lr) * BK + lk]);
#pragma unroll
        for (int m = 0; m < 4; ++m)
#pragma unroll
            for (int n = 0; n < 4; ++n)
                acc[m][n] = __builtin_amdgcn_mfma_f32_16x16x32_bf16(aF[m], bF[n], acc[m][n], 0, 0, 0);
        if (kt + 1 < NK) {
            store16f(&sA[cur ^ 1][soff], ra[0], ra[1], ra[2], ra[3]);
            store16f(&sB[cur ^ 1][soff], rb[0], rb[1], rb[2], rb[3]);
        }
        __syncthreads();
    }
    float* op = out + (size_t)k * (BLKDIM * BLKDIM);
    const int rbase = wr + (lane >> 4) * 4;
#pragma unroll
    for (int m = 0; m < 4; ++m)
#pragma unroll
        for (int n = 0; n < 4; ++n) {
            const int col = wc + n * 16 + lr;
#pragma unroll
            for (int j = 0; j < 4; ++j)
                op[(size_t)(rbase + m * 16 + j) * BLKDIM + col] = acc[m][n][j];
        }
}

extern "C" void kernel_launch(void* const* d_in, const int* in_sizes, int n_in,
                              void* d_out, int out_size, void* d_ws, size_t ws_size,
                              hipStream_t stream) {
    const float* x  = (const float*)d_in[0];
    const float* w1 = (const float*)d_in[1];
    const int* ri   = (const int*)d_in[2];
    const int* ci   = (const int*)d_in[3];
    float* out      = (float*)d_out;
    const int nnz   = in_sizes[2];
    const int nx    = in_sizes[0];   // 8388608
    const int nw    = in_sizes[1];   // 33554432

    const size_t need = ((size_t)nx + (size_t)nw) * sizeof(ushort);
    if (ws_size >= need && (nnz & 1) == 0) {
        ushort* xb = (ushort*)d_ws;
        ushort* wb = xb + nx;
        const int nx8 = nx / 8, nw8 = nw / 8;
        hipLaunchKernelGGL(cvt_bf16_kernel, dim3((nx8 + 255) / 256), dim3(256), 0, stream,
                           x, (uint4*)xb, nx8);
        hipLaunchKernelGGL(cvt_bf16_kernel, dim3((nw8 + 255) / 256), dim3(256), 0, stream,
                           w1, (uint4*)wb, nw8);
        hipLaunchKernelGGL(sdd_pair_kernel, dim3(nnz / 2), dim3(512), 0, stream,
                           xb, wb, ri, ci, out);
    } else {
        hipLaunchKernelGGL(sdd_bf16_kernel, dim3(nnz), dim3(256), 0, stream,
                           x, w1, ri, ci, out);
    }
}